// Round 4
// baseline (392.413 us; speedup 1.0000x reference)
//
#include <hip/hip_runtime.h>
#include <hip/hip_bf16.h>

typedef __attribute__((ext_vector_type(8))) __bf16 bf16x8;
typedef __attribute__((ext_vector_type(8))) short short8;
typedef __attribute__((ext_vector_type(4))) float f32x4;

#define BM 128
#define BN 128
#define BK 32
#define LDSS 40  // LDS row stride (bf16): 80B rows -> 2-way bank aliasing (free, m136)

__device__ inline unsigned short f2bf(float f) {  // RNE fp32->bf16 (finite inputs)
    union { float f; unsigned u; } v; v.f = f;
    unsigned r = (v.u + 0x7FFFu + ((v.u >> 16) & 1u)) >> 16;
    return (unsigned short)r;
}

// dtype probe: even-indexed ushorts of a bf16 buffer are sane bf16 exponents
// (~100% in [0x60,0x88]); of an fp32 buffer they are uniform mantissa bits (~16%).
__global__ void detect_dtype(const unsigned short* __restrict__ x, int* __restrict__ flag)
{
    const int tid = threadIdx.x;
    int cnt = 0;
    for (int i = tid; i < 1024; i += 256) {
        unsigned e = (x[2 * i] >> 7) & 0xFFu;
        cnt += (e >= 0x60u && e <= 0x88u) ? 1 : 0;
    }
    #pragma unroll
    for (int o = 32; o >= 1; o >>= 1) cnt += __shfl_xor(cnt, o, 64);
    __shared__ int red[4];
    if ((tid & 63) == 0) red[tid >> 6] = cnt;
    __syncthreads();
    if (tid == 0) {
        int t = red[0] + red[1] + red[2] + red[3];
        *flag = (t >= 512) ? 0 : 1;  // 0 = bf16 world, 1 = fp32 world
    }
}

__device__ inline short8 load_bf8(const void* base, long e, int isF32)
{
    if (isF32) {
        const float* p = (const float*)base + e;
        f32x4 f0 = *(const f32x4*)p;
        f32x4 f1 = *(const f32x4*)(p + 4);
        union { short8 s; unsigned short u[8]; } pk;
        #pragma unroll
        for (int i = 0; i < 4; i++) { pk.u[i] = f2bf(f0[i]); pk.u[4 + i] = f2bf(f1[i]); }
        return pk.s;
    }
    return *(const short8*)((const short*)base + e);
}

// C = A @ Bt^T. A [M][K] (lda), Bt [N][K] (ldb); all offsets/strides in ELEMENTS.
// oA/oB: base element offsets. aExt/bExt: dtype = flag ? fp32 : bf16 (0 = bf16 always).
// outKind: 0 bf16, 1 fp32, 2 external (flag ? fp32 : bf16).
// mode 0 plain; 1 causal tile-skip (global q row = q0+m); 2 causal k-limit.
__global__ __launch_bounds__(256, 2)
void gemm_bt(const void* __restrict__ Aall, const void* __restrict__ Btall,
             void* __restrict__ Call, int K, int lda, int ldb, int ldc,
             long oA, long oB, long oC, long sA, long sB, long sC,
             float scale, int mode, int q0,
             const int* __restrict__ dtf, int aExt, int bExt, int outKind)
{
    const int dt = *dtf;
    const int aF = aExt & dt, bF = bExt & dt;
    const int z = blockIdx.z;
    const long aBase = oA + (long)z * sA;
    const long bBase = oB + (long)z * sB;
    const long cBase = oC + (long)z * sC;

    const int m0 = blockIdx.y * BM;
    const int n0 = blockIdx.x * BN;
    if (mode == 1 && n0 >= q0 + m0 + BM) return;
    int kmax = K;
    if (mode == 2) kmax = min(K, q0 + m0 + BM);

    __shared__ __align__(16) short As[BM * LDSS];
    __shared__ __align__(16) short Bs[BN * LDSS];

    const int tid  = threadIdx.x;
    const int wave = tid >> 6;
    const int lane = tid & 63;
    const int wm = (wave >> 1) * 64;
    const int wn = (wave & 1) * 64;
    const int lrow = lane & 15;
    const int quad = lane >> 4;
    const int srow = tid >> 2;
    const int scol = (tid & 3) * 8;

    f32x4 acc[4][4];
    #pragma unroll
    for (int i = 0; i < 4; i++)
        #pragma unroll
        for (int j = 0; j < 4; j++) {
            f32x4 zero = {0.f, 0.f, 0.f, 0.f};
            acc[i][j] = zero;
        }

    for (int k0 = 0; k0 < kmax; k0 += BK) {
        short8 a0 = load_bf8(Aall,  aBase + (long)(m0 + srow)      * lda + k0 + scol, aF);
        short8 a1 = load_bf8(Aall,  aBase + (long)(m0 + srow + 64) * lda + k0 + scol, aF);
        short8 b0 = load_bf8(Btall, bBase + (long)(n0 + srow)      * ldb + k0 + scol, bF);
        short8 b1 = load_bf8(Btall, bBase + (long)(n0 + srow + 64) * ldb + k0 + scol, bF);
        __syncthreads();
        *(short8*)&As[(srow)      * LDSS + scol] = a0;
        *(short8*)&As[(srow + 64) * LDSS + scol] = a1;
        *(short8*)&Bs[(srow)      * LDSS + scol] = b0;
        *(short8*)&Bs[(srow + 64) * LDSS + scol] = b1;
        __syncthreads();

        bf16x8 af[4], bfr[4];
        #pragma unroll
        for (int i = 0; i < 4; i++) {
            af[i]  = *(const bf16x8*)&As[(wm + i * 16 + lrow) * LDSS + quad * 8];
            bfr[i] = *(const bf16x8*)&Bs[(wn + i * 16 + lrow) * LDSS + quad * 8];
        }
        #pragma unroll
        for (int i = 0; i < 4; i++)
            #pragma unroll
            for (int j = 0; j < 4; j++)
                acc[i][j] = __builtin_amdgcn_mfma_f32_16x16x32_bf16(af[i], bfr[j], acc[i][j], 0, 0, 0);
    }

    const int oF32 = (outKind == 1) | ((outKind == 2) & dt);
    // C/D layout (m89-verified): col = lane&15, row = quad*4 + reg
    #pragma unroll
    for (int i = 0; i < 4; i++) {
        const int mr = m0 + wm + i * 16 + quad * 4;
        #pragma unroll
        for (int j = 0; j < 4; j++) {
            const int nc = n0 + wn + j * 16 + lrow;
            #pragma unroll
            for (int r = 0; r < 4; r++) {
                const long ofs = cBase + (long)(mr + r) * ldc + nc;
                const float v = acc[i][j][r] * scale;
                if (oF32) ((float*)Call)[ofs] = v;
                else      ((unsigned short*)Call)[ofs] = f2bf(v);
            }
        }
    }
}

// dst[c][r] = src[r][c]; src [R][C] at element offset oS + z*sS, dtype per flag
// if srcExt; dst bf16 at element offset z*sD.
__global__ __launch_bounds__(256)
void transpose_any(const void* __restrict__ src, unsigned short* __restrict__ dst,
                   int R, int C, long oS, long sS, long sD,
                   const int* __restrict__ dtf, int srcExt)
{
    const int dt = srcExt ? *dtf : 0;
    const int b = blockIdx.z;
    const long sb = oS + (long)b * sS;
    unsigned short* d = dst + (long)b * sD;
    __shared__ unsigned short t[64][65];
    const int c0 = blockIdx.x * 64, r0 = blockIdx.y * 64;
    const int tid = threadIdx.x;
    #pragma unroll
    for (int it = 0; it < 16; it++) {
        int idx = it * 256 + tid;
        int r = idx >> 6, c = idx & 63;
        long e = sb + (long)(r0 + r) * C + (c0 + c);
        t[r][c] = dt ? f2bf(((const float*)src)[e]) : ((const unsigned short*)src)[e];
    }
    __syncthreads();
    #pragma unroll
    for (int it = 0; it < 16; it++) {
        int idx = it * 256 + tid;
        int r = idx >> 6, c = idx & 63;
        d[(long)(c0 + r) * R + (r0 + c)] = t[c][r];
    }
}

// Sc chunk fp32 [ZB][CH][S]; row (global q0+r) softmaxed, written back IN PLACE
// as bf16 P in the first half of its own fp32 row (P lda = 2S).
__global__ __launch_bounds__(256)
void softmax_causal(float* __restrict__ Sc, int S, int CH, int q0)
{
    const int r = blockIdx.x, z = blockIdx.y;
    float* srow = Sc + ((long)z * CH + r) * S;
    unsigned short* prow = (unsigned short*)srow;
    const int n = q0 + r + 1;
    const int tid = threadIdx.x;
    const int lane = tid & 63, wave = tid >> 6;
    __shared__ float red[4];

    float lm = -1e30f;
    #pragma unroll
    for (int c = 0; c < 8; c++) {
        int j = c * 256 + tid;
        if (j < n) lm = fmaxf(lm, srow[j]);
    }
    #pragma unroll
    for (int o = 32; o >= 1; o >>= 1) lm = fmaxf(lm, __shfl_xor(lm, o, 64));
    if (lane == 0) red[wave] = lm;
    __syncthreads();
    const float m = fmaxf(fmaxf(red[0], red[1]), fmaxf(red[2], red[3]));
    __syncthreads();

    float ev[8];
    float ls = 0.f;
    #pragma unroll
    for (int c = 0; c < 8; c++) {
        int j = c * 256 + tid;
        float e = (j < n) ? __expf(srow[j] - m) : 0.f;
        ev[c] = e;
        ls += e;
    }
    #pragma unroll
    for (int o = 32; o >= 1; o >>= 1) ls += __shfl_xor(ls, o, 64);
    if (lane == 0) red[wave] = ls;
    __syncthreads();   // all fp32 reads done before aliasing bf16 writes
    const float inv = 1.0f / (red[0] + red[1] + red[2] + red[3]);

    #pragma unroll
    for (int c = 0; c < 8; c++) {
        int j = c * 256 + tid;
        prow[j] = f2bf(j < n ? ev[c] * inv : 0.f);
    }
}

__global__ __launch_bounds__(256)
void fill_zero(void* o, long n, const int* dtf)
{
    long i = (long)blockIdx.x * 256 + threadIdx.x;
    if (i < n) {
        if (*dtf) ((float*)o)[i] = 0.f;
        else ((unsigned short*)o)[i] = 0;
    }
}

extern "C" void kernel_launch(void* const* d_in, const int* in_sizes, int n_in,
                              void* d_out, int out_size, void* d_ws, size_t ws_size,
                              hipStream_t stream)
{
    const int B = 4, S = 2048, D = 1024;
    const void* x  = d_in[0];
    const void* Qw = d_in[1];
    const void* Kw = d_in[2];
    const void* Vw = d_in[3];
    (void)in_sizes; (void)n_in; (void)out_size;

    // Associativity: scores = X (QwKw^T/32) X^T ;  out = (P X) Vw.
    int* dtf = (int*)d_ws;
    char* p = (char*)d_ws + 256;
    const size_t avail = (ws_size > 256) ? ws_size - 256 : 0;

    const int cfgs[15][2] = {{4,2048},{4,1024},{2,2048},{4,512},{2,1024},{1,2048},
                             {4,256},{2,512},{1,1024},{4,128},{2,256},{1,512},
                             {2,128},{1,256},{1,128}};
    int ZB = 0, CH = 0;
    for (int i = 0; i < 15; i++) {
        size_t need = ((size_t)4 << 20)
                    + (size_t)cfgs[i][0] * ((size_t)4 << 20)
                    + (size_t)cfgs[i][0] * cfgs[i][1] * (4 * (size_t)D + 4 * (size_t)S);
        if (need <= avail) { ZB = cfgs[i][0]; CH = cfgs[i][1]; break; }
    }

    detect_dtype<<<1, 256, 0, stream>>>((const unsigned short*)x, dtf);

    const long nOut = (long)B * S * D;
    if (ZB == 0) {  // below 9.5MB floor: diagnostic zeros (absmax would read 3.140625)
        fill_zero<<<dim3((unsigned)((nOut + 255) / 256)), 256, 0, stream>>>(d_out, nOut, dtf);
        return;
    }

    unsigned short* W2T = (unsigned short*)p; p += (size_t)2 << 20;
    unsigned short* VwT = (unsigned short*)p; p += (size_t)2 << 20;
    unsigned short* Xt  = (unsigned short*)p; p += (size_t)ZB * ((size_t)4 << 20);
    unsigned short* G   = (unsigned short*)p; p += (size_t)ZB * CH * D * 2;
    unsigned short* T   = (unsigned short*)p; p += (size_t)ZB * CH * D * 2;
    float* Sc = (float*)p;

    // 1. W2T = Kw Qw^T / 32  (= (QwKw^T)^T/32); A=Kw ext, Bt=Qw ext, out bf16
    gemm_bt<<<dim3(D / BN, D / BM, 1), 256, 0, stream>>>(
        Kw, Qw, W2T, D, D, D, D, 0L, 0L, 0L, 0L, 0L, 0L,
        0.03125f, 0, 0, dtf, 1, 1, 0);

    // 2. VwT[n][d] = Vw[d][n]
    transpose_any<<<dim3(16, 16, 1), 256, 0, stream>>>(Vw, VwT, D, D, 0L, 0L, 0L, dtf, 1);

    for (int b0 = 0; b0 < B; b0 += ZB) {
        const long xb = (long)b0 * S * D;  // element offset of batch b0 in x

        // 3. Xt[z][d][s] = x[b0+z][s][d]
        transpose_any<<<dim3(D / 64, S / 64, ZB), 256, 0, stream>>>(
            x, Xt, S, D, xb, (long)S * D, (long)D * S, dtf, 1);

        for (int q0 = 0; q0 < S; q0 += CH) {
            // 4. G = X_chunk @ W2   (A = x ext, Bt = W2T int, out bf16)
            gemm_bt<<<dim3(D / BN, CH / BM, ZB), 256, 0, stream>>>(
                x, W2T, G, D, D, D, D,
                xb + (long)q0 * D, 0L, 0L, (long)S * D, 0L, (long)CH * D,
                1.0f, 0, 0, dtf, 1, 0, 0);

            // 5. Sc = G @ x^T (Bt = x ext), causal tile-skip, out fp32
            gemm_bt<<<dim3(S / BN, CH / BM, ZB), 256, 0, stream>>>(
                G, x, Sc, D, D, D, S,
                0L, xb, 0L, (long)CH * D, (long)S * D, (long)CH * S,
                1.0f, 1, q0, dtf, 0, 1, 1);

            // 6. softmax in place -> P (bf16, lda 2S)
            softmax_causal<<<dim3(CH, ZB), 256, 0, stream>>>(Sc, S, CH, q0);

            // 7. T = P @ X (A = P int lda 2S, Bt = Xt int), causal k-limit
            gemm_bt<<<dim3(D / BN, CH / BM, ZB), 256, 0, stream>>>(
                Sc, Xt, T, S, 2 * S, S, D,
                0L, 0L, 0L, (long)CH * 2 * S, (long)D * S, (long)CH * D,
                1.0f, 2, q0, dtf, 0, 0, 0);

            // 8. O_chunk = T @ Vw (Bt = VwT int), out = external dtype
            gemm_bt<<<dim3(D / BN, CH / BM, ZB), 256, 0, stream>>>(
                T, VwT, d_out, D, D, D, D,
                0L, 0L, (long)b0 * S * D + (long)q0 * D, (long)CH * D, 0L, (long)S * D,
                1.0f, 0, 0, dtf, 0, 0, 2);
        }
    }
}

// Round 5
// 363.485 us; speedup vs baseline: 1.0796x; 1.0796x over previous
//
#include <hip/hip_runtime.h>
#include <hip/hip_bf16.h>

typedef __attribute__((ext_vector_type(8))) __bf16 bf16x8;
typedef __attribute__((ext_vector_type(8))) short short8;
typedef __attribute__((ext_vector_type(4))) float f32x4;

#define BM 128
#define BN 128
#define BK 32
#define LDSS 40  // LDS row stride (bf16): 80B rows -> 2-way bank aliasing (free, m136)

__device__ inline unsigned short f2bf(float f) {  // RNE fp32->bf16
    union { float f; unsigned u; } v; v.f = f;
    unsigned r = (v.u + 0x7FFFu + ((v.u >> 16) & 1u)) >> 16;
    return (unsigned short)r;
}

// dtype probe: even ushorts of bf16 N(0,1) data have sane exponents (~100% in
// [0x60,0x88]); of fp32 data they are uniform mantissa bits (~16%).
__global__ void detect_dtype(const unsigned short* __restrict__ x, int* __restrict__ flag)
{
    const int tid = threadIdx.x;
    int cnt = 0;
    for (int i = tid; i < 1024; i += 256) {
        unsigned e = (x[2 * i] >> 7) & 0xFFu;
        cnt += (e >= 0x60u && e <= 0x88u) ? 1 : 0;
    }
    #pragma unroll
    for (int o = 32; o >= 1; o >>= 1) cnt += __shfl_xor(cnt, o, 64);
    __shared__ int red[4];
    if ((tid & 63) == 0) red[tid >> 6] = cnt;
    __syncthreads();
    if (tid == 0) {
        int t = red[0] + red[1] + red[2] + red[3];
        *flag = (t >= 512) ? 0 : 1;  // 0 = bf16 world, 1 = fp32 world
    }
}

// Raw (unconverted) staging load: fp32 path keeps raw f32x4 pair so the vmcnt
// wait lands at the conversion site (next iter's LDS write), not before MFMA.
template <int EXT>
struct Staged {
    f32x4 lo, hi;
    short8 s;
    __device__ inline void load(const void* base, long e, int isF32) {
        if (EXT && isF32) {
            const float* p = (const float*)base + e;
            lo = *(const f32x4*)p;
            hi = *(const f32x4*)(p + 4);
        } else {
            s = *(const short8*)((const short*)base + e);
        }
    }
    __device__ inline short8 conv(int isF32) const {
        if (EXT && isF32) {
            union { short8 s; unsigned short u[8]; } pk;
            #pragma unroll
            for (int i = 0; i < 4; i++) { pk.u[i] = f2bf(lo[i]); pk.u[4 + i] = f2bf(hi[i]); }
            return pk.s;
        }
        return s;
    }
};

// C = A @ Bt^T. A [M][K] (lda), Bt [N][K] (ldb); offsets/strides in ELEMENTS.
// AE/BE: operand may be external (flag ? fp32 : bf16); 0 = always-bf16 internal.
// outKind: 0 bf16, 1 fp32, 2 external. mode: 0 plain grid(x=n,y=m);
// 1 enumerated causal tiles, blockIdx.x -> (mt,nt), q0 = chunk row offset;
// 2 causal k-limit kmax = min(K, q0 + m0 + BM).
// K-loop is software-pipelined: raw prefetch of tile k+1 issues before the
// MFMAs of tile k so the ~900cyc global latency overlaps compute (round-4
// counters: MfmaUtil 1%, Occ 2.7% -> latency-serialization bound).
template <int AE, int BE>
__global__ __launch_bounds__(256, 2)
void gemm_bt(const void* __restrict__ Aall, const void* __restrict__ Btall,
             void* __restrict__ Call, int K, int lda, int ldb, int ldc,
             long oA, long oB, long oC, long sA, long sB, long sC,
             float scale, int mode, int q0,
             const int* __restrict__ dtf, int outKind)
{
    const int dt = *dtf;
    const int aF = AE ? dt : 0, bF = BE ? dt : 0;
    const int z = blockIdx.z;
    const long aBase = oA + (long)z * sA;
    const long bBase = oB + (long)z * sB;
    const long cBase = oC + (long)z * sC;

    int mt, nt;
    if (mode == 1) {  // decode linear id over the causal tile triangle
        int rem = blockIdx.x, r = 0, w = q0 / BN + 1;
        while (rem >= w) { rem -= w; r++; w++; }
        mt = r; nt = rem;
    } else { mt = blockIdx.y; nt = blockIdx.x; }
    const int m0 = mt * BM;
    const int n0 = nt * BN;
    int kmax = K;
    if (mode == 2) kmax = min(K, q0 + m0 + BM);

    __shared__ __align__(16) short As[BM * LDSS];
    __shared__ __align__(16) short Bs[BN * LDSS];

    const int tid  = threadIdx.x;
    const int wave = tid >> 6;
    const int lane = tid & 63;
    const int wm = (wave >> 1) * 64;
    const int wn = (wave & 1) * 64;
    const int lrow = lane & 15;
    const int quad = lane >> 4;
    const int srow = tid >> 2;
    const int scol = (tid & 3) * 8;

    f32x4 acc[4][4];
    #pragma unroll
    for (int i = 0; i < 4; i++)
        #pragma unroll
        for (int j = 0; j < 4; j++) {
            f32x4 zero = {0.f, 0.f, 0.f, 0.f};
            acc[i][j] = zero;
        }

    const long aR0 = aBase + (long)(m0 + srow) * lda + scol;
    const long aR1 = aBase + (long)(m0 + srow + 64) * lda + scol;
    const long bR0 = bBase + (long)(n0 + srow) * ldb + scol;
    const long bR1 = bBase + (long)(n0 + srow + 64) * ldb + scol;

    Staged<AE> a0, a1;
    Staged<BE> b0, b1;
    a0.load(Aall, aR0, aF);
    a1.load(Aall, aR1, aF);
    b0.load(Btall, bR0, bF);
    b1.load(Btall, bR1, bF);

    for (int k0 = 0; k0 < kmax; k0 += BK) {
        __syncthreads();   // prev iter's ds_reads done
        *(short8*)&As[(srow)      * LDSS + scol] = a0.conv(aF);
        *(short8*)&As[(srow + 64) * LDSS + scol] = a1.conv(aF);
        *(short8*)&Bs[(srow)      * LDSS + scol] = b0.conv(bF);
        *(short8*)&Bs[(srow + 64) * LDSS + scol] = b1.conv(bF);
        __syncthreads();   // LDS ready

        const int kn = k0 + BK;
        if (kn < kmax) {   // issue next tile's loads; results not needed until next iter
            a0.load(Aall, aR0 + kn, aF);
            a1.load(Aall, aR1 + kn, aF);
            b0.load(Btall, bR0 + kn, bF);
            b1.load(Btall, bR1 + kn, bF);
        }

        bf16x8 af[4], bfr[4];
        #pragma unroll
        for (int i = 0; i < 4; i++) {
            af[i]  = *(const bf16x8*)&As[(wm + i * 16 + lrow) * LDSS + quad * 8];
            bfr[i] = *(const bf16x8*)&Bs[(wn + i * 16 + lrow) * LDSS + quad * 8];
        }
        #pragma unroll
        for (int i = 0; i < 4; i++)
            #pragma unroll
            for (int j = 0; j < 4; j++)
                acc[i][j] = __builtin_amdgcn_mfma_f32_16x16x32_bf16(af[i], bfr[j], acc[i][j], 0, 0, 0);
    }

    const int oF32 = (outKind == 1) | ((outKind == 2) & dt);
    // C/D layout (m89-verified): col = lane&15, row = quad*4 + reg
    #pragma unroll
    for (int i = 0; i < 4; i++) {
        const int mr = m0 + wm + i * 16 + quad * 4;
        #pragma unroll
        for (int j = 0; j < 4; j++) {
            const int nc = n0 + wn + j * 16 + lrow;
            #pragma unroll
            for (int r = 0; r < 4; r++) {
                const long ofs = cBase + (long)(mr + r) * ldc + nc;
                const float v = acc[i][j][r] * scale;
                if (oF32) ((float*)Call)[ofs] = v;
                else      ((unsigned short*)Call)[ofs] = f2bf(v);
            }
        }
    }
}

// dst[c][r] = src[r][c]; src [R][C] at element offset oS + z*sS (dtype per flag
// if srcExt); dst bf16 at z*sD.
__global__ __launch_bounds__(256)
void transpose_any(const void* __restrict__ src, unsigned short* __restrict__ dst,
                   int R, int C, long oS, long sS, long sD,
                   const int* __restrict__ dtf, int srcExt)
{
    const int dt = srcExt ? *dtf : 0;
    const int b = blockIdx.z;
    const long sb = oS + (long)b * sS;
    unsigned short* d = dst + (long)b * sD;
    __shared__ unsigned short t[64][65];
    const int c0 = blockIdx.x * 64, r0 = blockIdx.y * 64;
    const int tid = threadIdx.x;
    #pragma unroll
    for (int it = 0; it < 16; it++) {
        int idx = it * 256 + tid;
        int r = idx >> 6, c = idx & 63;
        long e = sb + (long)(r0 + r) * C + (c0 + c);
        t[r][c] = dt ? f2bf(((const float*)src)[e]) : ((const unsigned short*)src)[e];
    }
    __syncthreads();
    #pragma unroll
    for (int it = 0; it < 16; it++) {
        int idx = it * 256 + tid;
        int r = idx >> 6, c = idx & 63;
        d[(long)(c0 + r) * R + (r0 + c)] = t[c][r];
    }
}

// Sc chunk fp32 [ZB][CH][S]; row (global q0+r) softmaxed, written back IN PLACE
// as bf16 P in the first half of its own fp32 row (P lda = 2S).
__global__ __launch_bounds__(256)
void softmax_causal(float* __restrict__ Sc, int S, int CH, int q0)
{
    const int r = blockIdx.x, z = blockIdx.y;
    float* srow = Sc + ((long)z * CH + r) * S;
    unsigned short* prow = (unsigned short*)srow;
    const int n = q0 + r + 1;
    const int tid = threadIdx.x;
    const int lane = tid & 63, wave = tid >> 6;
    __shared__ float red[4];

    float lm = -1e30f;
    #pragma unroll
    for (int c = 0; c < 8; c++) {
        int j = c * 256 + tid;
        if (j < n) lm = fmaxf(lm, srow[j]);
    }
    #pragma unroll
    for (int o = 32; o >= 1; o >>= 1) lm = fmaxf(lm, __shfl_xor(lm, o, 64));
    if (lane == 0) red[wave] = lm;
    __syncthreads();
    const float m = fmaxf(fmaxf(red[0], red[1]), fmaxf(red[2], red[3]));
    __syncthreads();

    float ev[8];
    float ls = 0.f;
    #pragma unroll
    for (int c = 0; c < 8; c++) {
        int j = c * 256 + tid;
        float e = (j < n) ? __expf(srow[j] - m) : 0.f;
        ev[c] = e;
        ls += e;
    }
    #pragma unroll
    for (int o = 32; o >= 1; o >>= 1) ls += __shfl_xor(ls, o, 64);
    if (lane == 0) red[wave] = ls;
    __syncthreads();   // all fp32 reads done before aliasing bf16 writes
    const float inv = 1.0f / (red[0] + red[1] + red[2] + red[3]);

    #pragma unroll
    for (int c = 0; c < 8; c++) {
        int j = c * 256 + tid;
        prow[j] = f2bf(j < n ? ev[c] * inv : 0.f);
    }
}

__global__ __launch_bounds__(256)
void fill_zero(void* o, long n, const int* dtf)
{
    long i = (long)blockIdx.x * 256 + threadIdx.x;
    if (i < n) {
        if (*dtf) ((float*)o)[i] = 0.f;
        else ((unsigned short*)o)[i] = 0;
    }
}

extern "C" void kernel_launch(void* const* d_in, const int* in_sizes, int n_in,
                              void* d_out, int out_size, void* d_ws, size_t ws_size,
                              hipStream_t stream)
{
    const int B = 4, S = 2048, D = 1024;
    const void* x  = d_in[0];
    const void* Qw = d_in[1];
    const void* Kw = d_in[2];
    const void* Vw = d_in[3];
    (void)in_sizes; (void)n_in; (void)out_size;

    // Associativity: scores = X (QwKw^T/32) X^T ;  out = (P X) Vw.
    // ws: dtf | W2T 2MB | VwT 2MB | Xt 16MB | GT 16MB (G then overwritten by T) |
    //     Sc fp32 [ZB][CH][S].
    int* dtf = (int*)d_ws;
    char* p = (char*)d_ws + 4096;
    const size_t fixed = 4096 + ((size_t)36 << 20);

    const int cfgs[7][2] = {{4,2048},{2,2048},{1,2048},{1,1024},{1,512},{1,256},{1,128}};
    int ZB = 0, CH = 0;
    for (int i = 0; i < 7; i++) {
        size_t need = fixed + (size_t)cfgs[i][0] * cfgs[i][1] * S * 4;
        if (need <= ws_size) { ZB = cfgs[i][0]; CH = cfgs[i][1]; break; }
    }

    detect_dtype<<<1, 256, 0, stream>>>((const unsigned short*)x, dtf);

    const long nOut = (long)B * S * D;
    if (ZB == 0) {  // < 37MB floor: diagnostic zeros (absmax would read 3.140625)
        fill_zero<<<dim3((unsigned)((nOut + 255) / 256)), 256, 0, stream>>>(d_out, nOut, dtf);
        return;
    }

    unsigned short* W2T = (unsigned short*)p; p += (size_t)2 << 20;
    unsigned short* VwT = (unsigned short*)p; p += (size_t)2 << 20;
    unsigned short* Xt  = (unsigned short*)p; p += (size_t)16 << 20;
    unsigned short* GT  = (unsigned short*)p; p += (size_t)16 << 20;
    float* Sc = (float*)p;

    // 1. W2T = Kw Qw^T / 32 (= (QwKw^T)^T/32); out bf16
    gemm_bt<1, 1><<<dim3(D / BN, D / BM, 1), 256, 0, stream>>>(
        Kw, Qw, W2T, D, D, D, D, 0L, 0L, 0L, 0L, 0L, 0L,
        0.03125f, 0, 0, dtf, 0);

    // 2. VwT[n][d] = Vw[d][n]
    transpose_any<<<dim3(16, 16, 1), 256, 0, stream>>>(Vw, VwT, D, D, 0L, 0L, 0L, dtf, 1);

    // 3. Xt[b][d][s] = x[b][s][d], all batches
    transpose_any<<<dim3(D / 64, S / 64, B), 256, 0, stream>>>(
        x, Xt, S, D, 0L, (long)S * D, (long)D * S, dtf, 1);

    // 4. G = X @ W2, full batch (8192x1024 rows -> 512 blocks)
    gemm_bt<1, 0><<<dim3(D / BN, (B * S) / BM, 1), 256, 0, stream>>>(
        x, W2T, GT, D, D, D, D, 0L, 0L, 0L, 0L, 0L, 0L,
        1.0f, 0, 0, dtf, 0);

    // 5. chunked attention core: Sc -> softmax(in place) -> T (overwrites G rows)
    for (int b0 = 0; b0 < B; b0 += ZB) {
        for (int q0 = 0; q0 < S; q0 += CH) {
            const int base = q0 / BN, R = CH / BM;
            const int ntiles = R * (base + 1) + R * (R - 1) / 2;  // valid causal tiles

            // Sc = G_chunk @ x^T (uniform K=D per tile; enumerated causal grid)
            gemm_bt<0, 1><<<dim3(ntiles, 1, ZB), 256, 0, stream>>>(
                GT, x, Sc, D, D, D, S,
                (long)b0 * S * D + (long)q0 * D, (long)b0 * S * D, 0L,
                (long)S * D, (long)S * D, (long)CH * S,
                1.0f, 1, q0, dtf, 1);

            softmax_causal<<<dim3(CH, ZB), 256, 0, stream>>>(Sc, S, CH, q0);

            // T = P @ X (A = P bf16 lda 2S; Bt = Xt), causal k-limit; writes GT rows
            gemm_bt<0, 0><<<dim3(D / BN, CH / BM, ZB), 256, 0, stream>>>(
                Sc, Xt, GT, S, 2 * S, S, D,
                0L, (long)b0 * D * S, (long)b0 * S * D + (long)q0 * D,
                (long)CH * 2 * S, (long)D * S, (long)S * D,
                1.0f, 2, q0, dtf, 0);
        }
    }

    // 6. out = T @ Vw, full batch (outKind 2: dtype per flag)
    gemm_bt<0, 0><<<dim3(D / BN, (B * S) / BM, 1), 256, 0, stream>>>(
        GT, VwT, d_out, D, D, D, D, 0L, 0L, 0L, 0L, 0L, 0L,
        1.0f, 0, 0, dtf, 2);
}

// Round 6
// 352.015 us; speedup vs baseline: 1.1148x; 1.0326x over previous
//
#include <hip/hip_runtime.h>
#include <hip/hip_bf16.h>

typedef __attribute__((ext_vector_type(8))) __bf16 bf16x8;
typedef __attribute__((ext_vector_type(8))) short short8;
typedef __attribute__((ext_vector_type(4))) float f32x4;

#define BM 128
#define BN 128
#define BK 32
#define LDSS 40  // LDS row stride (bf16): 80B rows -> 2-way bank aliasing (free, m136)

__device__ inline unsigned short f2bf(float f) {  // RNE fp32->bf16
    union { float f; unsigned u; } v; v.f = f;
    unsigned r = (v.u + 0x7FFFu + ((v.u >> 16) & 1u)) >> 16;
    return (unsigned short)r;
}

// dtype probe: even ushorts of bf16 N(0,1) data have sane exponents (~100% in
// [0x60,0x88]); of fp32 data they are uniform mantissa bits (~16%).
__global__ void detect_dtype(const unsigned short* __restrict__ x, int* __restrict__ flag)
{
    const int tid = threadIdx.x;
    int cnt = 0;
    for (int i = tid; i < 1024; i += 256) {
        unsigned e = (x[2 * i] >> 7) & 0xFFu;
        cnt += (e >= 0x60u && e <= 0x88u) ? 1 : 0;
    }
    #pragma unroll
    for (int o = 32; o >= 1; o >>= 1) cnt += __shfl_xor(cnt, o, 64);
    __shared__ int red[4];
    if ((tid & 63) == 0) red[tid >> 6] = cnt;
    __syncthreads();
    if (tid == 0) {
        int t = red[0] + red[1] + red[2] + red[3];
        *flag = (t >= 512) ? 0 : 1;  // 0 = bf16 world, 1 = fp32 world
    }
}

// Raw (unconverted) staging load: fp32 path keeps raw f32x4 pair so the vmcnt
// wait lands at the conversion site (next iter's LDS write), not before MFMA.
template <int EXT>
struct Staged {
    f32x4 lo, hi;
    short8 s;
    __device__ inline void load(const void* base, long e, int isF32) {
        if (EXT && isF32) {
            const float* p = (const float*)base + e;
            lo = *(const f32x4*)p;
            hi = *(const f32x4*)(p + 4);
        } else {
            s = *(const short8*)((const short*)base + e);
        }
    }
    __device__ inline short8 conv(int isF32) const {
        if (EXT && isF32) {
            union { short8 s; unsigned short u[8]; } pk;
            #pragma unroll
            for (int i = 0; i < 4; i++) { pk.u[i] = f2bf(lo[i]); pk.u[4 + i] = f2bf(hi[i]); }
            return pk.s;
        }
        return s;
    }
};

// C = A @ Bt^T. A [M][K] (lda), Bt [N][K] (ldb); offsets/strides in ELEMENTS.
// AE/BE: operand may be external (flag ? fp32 : bf16); 0 = always-bf16 internal.
// outKind: 0 bf16, 1 fp32, 2 external. mode: 0 plain grid(x=n,y=m);
// 1 enumerated causal tiles (blockIdx.x -> (mt,nt), q0 = chunk row offset);
// 2 causal k-limit kmax = min(K, q0 + m0 + BM).
// NOTE: A/C deliberately NOT __restrict__ — G=QX@Kw^T and T=P@X reuse the same
// buffer in place (row-disjoint across blocks; reads precede epilogue writes
// within a block via data dependence).
template <int AE, int BE>
__global__ __launch_bounds__(256, 2)
void gemm_bt(const void* Aall, const void* __restrict__ Btall,
             void* Call, int K, int lda, int ldb, int ldc,
             long oA, long oB, long oC, long sA, long sB, long sC,
             float scale, int mode, int q0,
             const int* __restrict__ dtf, int outKind)
{
    const int dt = *dtf;
    const int aF = AE ? dt : 0, bF = BE ? dt : 0;
    const int z = blockIdx.z;
    const long aBase = oA + (long)z * sA;
    const long bBase = oB + (long)z * sB;
    const long cBase = oC + (long)z * sC;

    int mt, nt;
    if (mode == 1) {  // decode linear id over the causal tile triangle
        int rem = blockIdx.x, r = 0, w = q0 / BN + 1;
        while (rem >= w) { rem -= w; r++; w++; }
        mt = r; nt = rem;
    } else { mt = blockIdx.y; nt = blockIdx.x; }
    const int m0 = mt * BM;
    const int n0 = nt * BN;
    int kmax = K;
    if (mode == 2) kmax = min(K, q0 + m0 + BM);

    __shared__ __align__(16) short As[BM * LDSS];
    __shared__ __align__(16) short Bs[BN * LDSS];

    const int tid  = threadIdx.x;
    const int wave = tid >> 6;
    const int lane = tid & 63;
    const int wm = (wave >> 1) * 64;
    const int wn = (wave & 1) * 64;
    const int lrow = lane & 15;
    const int quad = lane >> 4;
    const int srow = tid >> 2;
    const int scol = (tid & 3) * 8;

    f32x4 acc[4][4];
    #pragma unroll
    for (int i = 0; i < 4; i++)
        #pragma unroll
        for (int j = 0; j < 4; j++) {
            f32x4 zero = {0.f, 0.f, 0.f, 0.f};
            acc[i][j] = zero;
        }

    const long aR0 = aBase + (long)(m0 + srow) * lda + scol;
    const long aR1 = aBase + (long)(m0 + srow + 64) * lda + scol;
    const long bR0 = bBase + (long)(n0 + srow) * ldb + scol;
    const long bR1 = bBase + (long)(n0 + srow + 64) * ldb + scol;

    Staged<AE> a0, a1;
    Staged<BE> b0, b1;
    a0.load(Aall, aR0, aF);
    a1.load(Aall, aR1, aF);
    b0.load(Btall, bR0, bF);
    b1.load(Btall, bR1, bF);

    for (int k0 = 0; k0 < kmax; k0 += BK) {
        __syncthreads();   // prev iter's ds_reads done
        *(short8*)&As[(srow)      * LDSS + scol] = a0.conv(aF);
        *(short8*)&As[(srow + 64) * LDSS + scol] = a1.conv(aF);
        *(short8*)&Bs[(srow)      * LDSS + scol] = b0.conv(bF);
        *(short8*)&Bs[(srow + 64) * LDSS + scol] = b1.conv(bF);
        __syncthreads();   // LDS ready

        const int kn = k0 + BK;
        if (kn < kmax) {   // next tile's loads in flight during this tile's MFMAs
            a0.load(Aall, aR0 + kn, aF);
            a1.load(Aall, aR1 + kn, aF);
            b0.load(Btall, bR0 + kn, bF);
            b1.load(Btall, bR1 + kn, bF);
        }

        bf16x8 af[4], bfr[4];
        #pragma unroll
        for (int i = 0; i < 4; i++) {
            af[i]  = *(const bf16x8*)&As[(wm + i * 16 + lrow) * LDSS + quad * 8];
            bfr[i] = *(const bf16x8*)&Bs[(wn + i * 16 + lrow) * LDSS + quad * 8];
        }
        #pragma unroll
        for (int i = 0; i < 4; i++)
            #pragma unroll
            for (int j = 0; j < 4; j++)
                acc[i][j] = __builtin_amdgcn_mfma_f32_16x16x32_bf16(af[i], bfr[j], acc[i][j], 0, 0, 0);
    }

    const int oF32 = (outKind == 1) | ((outKind == 2) & dt);
    // C/D layout (m89-verified): col = lane&15, row = quad*4 + reg
    #pragma unroll
    for (int i = 0; i < 4; i++) {
        const int mr = m0 + wm + i * 16 + quad * 4;
        #pragma unroll
        for (int j = 0; j < 4; j++) {
            const int nc = n0 + wn + j * 16 + lrow;
            #pragma unroll
            for (int r = 0; r < 4; r++) {
                const long ofs = cBase + (long)(mr + r) * ldc + nc;
                const float v = acc[i][j][r] * scale;
                if (oF32) ((float*)Call)[ofs] = v;
                else      ((unsigned short*)Call)[ofs] = f2bf(v);
            }
        }
    }
}

// dst[c][r] = src[r][c]; src [R][C] at element offset oS + z*sS (dtype per flag
// if srcExt); dst bf16 at z*sD.
__global__ __launch_bounds__(256)
void transpose_any(const void* __restrict__ src, unsigned short* __restrict__ dst,
                   int R, int C, long oS, long sS, long sD,
                   const int* __restrict__ dtf, int srcExt)
{
    const int dt = srcExt ? *dtf : 0;
    const int b = blockIdx.z;
    const long sb = oS + (long)b * sS;
    unsigned short* d = dst + (long)b * sD;
    __shared__ unsigned short t[64][65];
    const int c0 = blockIdx.x * 64, r0 = blockIdx.y * 64;
    const int tid = threadIdx.x;
    #pragma unroll
    for (int it = 0; it < 16; it++) {
        int idx = it * 256 + tid;
        int r = idx >> 6, c = idx & 63;
        long e = sb + (long)(r0 + r) * C + (c0 + c);
        t[r][c] = dt ? f2bf(((const float*)src)[e]) : ((const unsigned short*)src)[e];
    }
    __syncthreads();
    #pragma unroll
    for (int it = 0; it < 16; it++) {
        int idx = it * 256 + tid;
        int r = idx >> 6, c = idx & 63;
        d[(long)(c0 + r) * R + (r0 + c)] = t[c][r];
    }
}

// Sc chunk fp32 [ZB][CH][S]; row (global q0+r) softmaxed, written back IN PLACE
// as bf16 P in the first half of its own fp32 row (P lda = 2S).
__global__ __launch_bounds__(256)
void softmax_causal(float* __restrict__ Sc, int S, int CH, int q0)
{
    const int r = blockIdx.x, z = blockIdx.y;
    float* srow = Sc + ((long)z * CH + r) * S;
    unsigned short* prow = (unsigned short*)srow;
    const int n = q0 + r + 1;
    const int tid = threadIdx.x;
    const int lane = tid & 63, wave = tid >> 6;
    __shared__ float red[4];

    float lm = -1e30f;
    #pragma unroll
    for (int c = 0; c < 8; c++) {
        int j = c * 256 + tid;
        if (j < n) lm = fmaxf(lm, srow[j]);
    }
    #pragma unroll
    for (int o = 32; o >= 1; o >>= 1) lm = fmaxf(lm, __shfl_xor(lm, o, 64));
    if (lane == 0) red[wave] = lm;
    __syncthreads();
    const float m = fmaxf(fmaxf(red[0], red[1]), fmaxf(red[2], red[3]));
    __syncthreads();

    float ev[8];
    float ls = 0.f;
    #pragma unroll
    for (int c = 0; c < 8; c++) {
        int j = c * 256 + tid;
        float e = (j < n) ? __expf(srow[j] - m) : 0.f;
        ev[c] = e;
        ls += e;
    }
    #pragma unroll
    for (int o = 32; o >= 1; o >>= 1) ls += __shfl_xor(ls, o, 64);
    if (lane == 0) red[wave] = ls;
    __syncthreads();   // all fp32 reads done before aliasing bf16 writes
    const float inv = 1.0f / (red[0] + red[1] + red[2] + red[3]);

    #pragma unroll
    for (int c = 0; c < 8; c++) {
        int j = c * 256 + tid;
        prow[j] = f2bf(j < n ? ev[c] * inv : 0.f);
    }
}

__global__ __launch_bounds__(256)
void fill_zero(void* o, long n, const int* dtf)
{
    long i = (long)blockIdx.x * 256 + threadIdx.x;
    if (i < n) {
        if (*dtf) ((float*)o)[i] = 0.f;
        else ((unsigned short*)o)[i] = 0;
    }
}

extern "C" void kernel_launch(void* const* d_in, const int* in_sizes, int n_in,
                              void* d_out, int out_size, void* d_ws, size_t ws_size,
                              hipStream_t stream)
{
    const int B = 4, S = 2048, D = 1024;
    const void* x  = d_in[0];
    const void* Qw = d_in[1];
    const void* Kw = d_in[2];
    const void* Vw = d_in[3];
    (void)in_sizes; (void)n_in; (void)out_size;

    // scores = (X Qw) Kw^T X^T / 32 ;  out = (P X) Vw.   All GEMMs >= 512 blocks
    // except none — the tiny W2T straggler (r5: 80us @ Occ 2.7%) is gone.
    // ws: dtf | QwT 2MB | VwT 2MB | Xt 16MB | Buf 16MB (QX -> G in place -> T) |
    //     Sc fp32 [ZB][CH][S].
    int* dtf = (int*)d_ws;
    char* p = (char*)d_ws + 4096;
    const size_t fixed = 4096 + ((size_t)36 << 20);

    const int cfgs[7][2] = {{4,2048},{2,2048},{1,2048},{1,1024},{1,512},{1,256},{1,128}};
    int ZB = 0, CH = 0;
    for (int i = 0; i < 7; i++) {
        size_t need = fixed + (size_t)cfgs[i][0] * cfgs[i][1] * S * 4;
        if (need <= ws_size) { ZB = cfgs[i][0]; CH = cfgs[i][1]; break; }
    }

    detect_dtype<<<1, 256, 0, stream>>>((const unsigned short*)x, dtf);

    const long nOut = (long)B * S * D;
    if (ZB == 0) {  // < 37MB floor: diagnostic zeros (absmax would read 3.140625)
        fill_zero<<<dim3((unsigned)((nOut + 255) / 256)), 256, 0, stream>>>(d_out, nOut, dtf);
        return;
    }

    unsigned short* QwT = (unsigned short*)p; p += (size_t)2 << 20;
    unsigned short* VwT = (unsigned short*)p; p += (size_t)2 << 20;
    unsigned short* Xt  = (unsigned short*)p; p += (size_t)16 << 20;
    unsigned short* Buf = (unsigned short*)p; p += (size_t)16 << 20;
    float* Sc = (float*)p;

    // 1. QwT[b][a] = Qw[a][b]
    transpose_any<<<dim3(16, 16, 1), 256, 0, stream>>>(Qw, QwT, D, D, 0L, 0L, 0L, dtf, 1);

    // 2. QX = x @ Qw  (A = x ext, Bt = QwT int) -> Buf   [512 blocks]
    gemm_bt<1, 0><<<dim3(D / BN, (B * S) / BM, 1), 256, 0, stream>>>(
        x, QwT, Buf, D, D, D, D, 0L, 0L, 0L, 0L, 0L, 0L,
        1.0f, 0, 0, dtf, 0);

    // 3. G = QX @ Kw^T / 32, IN PLACE over Buf (Bt = Kw ext AS STORED:
    //    G[q][a] = sum_b QX[q][b] * Kw[a][b])   [512 blocks]
    gemm_bt<0, 1><<<dim3(D / BN, (B * S) / BM, 1), 256, 0, stream>>>(
        Buf, Kw, Buf, D, D, D, D, 0L, 0L, 0L, 0L, 0L, 0L,
        0.03125f, 0, 0, dtf, 0);

    // 4. Xt[b][d][s] = x[b][s][d]
    transpose_any<<<dim3(D / 64, S / 64, B), 256, 0, stream>>>(
        x, Xt, S, D, 0L, (long)S * D, (long)D * S, dtf, 1);

    // 5. VwT[n][d] = Vw[d][n]
    transpose_any<<<dim3(16, 16, 1), 256, 0, stream>>>(Vw, VwT, D, D, 0L, 0L, 0L, dtf, 1);

    // 6. chunked attention core: Sc -> softmax(in place) -> T (overwrites G rows)
    for (int b0 = 0; b0 < B; b0 += ZB) {
        for (int q0 = 0; q0 < S; q0 += CH) {
            const int base = q0 / BN, R = CH / BM;
            const int ntiles = R * (base + 1) + R * (R - 1) / 2;  // valid causal tiles

            // Sc = G_chunk @ x^T  (Bt = x ext as stored; enumerated causal grid)
            gemm_bt<0, 1><<<dim3(ntiles, 1, ZB), 256, 0, stream>>>(
                Buf, x, Sc, D, D, D, S,
                (long)b0 * S * D + (long)q0 * D, (long)b0 * S * D, 0L,
                (long)S * D, (long)S * D, (long)CH * S,
                1.0f, 1, q0, dtf, 1);

            softmax_causal<<<dim3(CH, ZB), 256, 0, stream>>>(Sc, S, CH, q0);

            // T = P @ X (A = P bf16 lda 2S; Bt = Xt), causal k-limit; writes Buf rows
            gemm_bt<0, 0><<<dim3(D / BN, CH / BM, ZB), 256, 0, stream>>>(
                Sc, Xt, Buf, S, 2 * S, S, D,
                0L, (long)b0 * D * S, (long)b0 * S * D + (long)q0 * D,
                (long)CH * 2 * S, (long)D * S, (long)S * D,
                1.0f, 2, q0, dtf, 0);
        }
    }

    // 7. out = T @ Vw  (Bt = VwT; outKind 2: dtype per flag)   [512 blocks]
    gemm_bt<0, 0><<<dim3(D / BN, (B * S) / BM, 1), 256, 0, stream>>>(
        Buf, VwT, d_out, D, D, D, D, 0L, 0L, 0L, 0L, 0L, 0L,
        1.0f, 0, 0, dtf, 2);
}